// Round 1
// baseline (195.575 us; speedup 1.0000x reference)
//
#include <hip/hip_runtime.h>
#include <hip/hip_bf16.h>

#define B_ 2
#define T_ 2048
#define C_ 1024
#define H_ 16
#define DH_ 64

typedef __attribute__((ext_vector_type(8))) short bf16x8;
typedef __attribute__((ext_vector_type(4))) float f32x4;

#define DEVI static __device__ __forceinline__

DEVI unsigned short f2bf(float f) {
  unsigned int u = __float_as_uint(f);
  u = (u + 0x7fffu + ((u >> 16) & 1u)) >> 16;
  return (unsigned short)u;
}

DEVI f32x4 mfma16(bf16x8 a, bf16x8 b, f32x4 c) {
  return __builtin_amdgcn_mfma_f32_16x16x32_bf16(a, b, c, 0, 0, 0);
}

DEVI void gload_lds16(const unsigned short* g, unsigned short* l) {
  __builtin_amdgcn_global_load_lds(
      (const __attribute__((address_space(1))) unsigned int*)g,
      (__attribute__((address_space(3))) unsigned int*)l, 16, 0, 0);
}

// ---- fp32 -> bf16 cast, 4 elems/thread ----
__global__ void cast_kernel(const float* __restrict__ in,
                            unsigned short* __restrict__ out, int n4) {
  int i = blockIdx.x * blockDim.x + threadIdx.x;
  if (i >= n4) return;
  float4 v = reinterpret_cast<const float4*>(in)[i];
  ushort4 o;
  o.x = f2bf(v.x); o.y = f2bf(v.y); o.z = f2bf(v.z); o.w = f2bf(v.w);
  reinterpret_cast<ushort4*>(out)[i] = o;
}

// ---- transpose + cast: in[R][C] fp32 -> out[C][R] bf16 ----
__global__ void transpose_cast_kernel(const float* __restrict__ in,
                                      unsigned short* __restrict__ out,
                                      int R, int C) {
  __shared__ float tile[32][33];
  int c0 = blockIdx.x * 32, r0 = blockIdx.y * 32;
  int tx = threadIdx.x, ty = threadIdx.y;
#pragma unroll
  for (int j = 0; j < 32; j += 8)
    tile[ty + j][tx] = in[(size_t)(r0 + ty + j) * C + c0 + tx];
  __syncthreads();
#pragma unroll
  for (int j = 0; j < 32; j += 8)
    out[(size_t)(c0 + ty + j) * R + r0 + tx] = f2bf(tile[tx][ty + j]);
}

// ---- GEMM C[M,N] = A[M,K] @ Bt[N,K]^T + bias  (m97 structure) ----
// EPI=1: scatter into q[B,H,T,64], k[B,H,T,64], vT[B,H,64,T] (bf16)
// EPI=2: fp32 row-major out
template <int EPI>
__global__ __launch_bounds__(256) void gemm_bt(
    const unsigned short* __restrict__ A, const unsigned short* __restrict__ Bt,
    const float* __restrict__ bias, void* __restrict__ outp,
    int Mdim, int Ndim, int Kdim,
    unsigned short* __restrict__ qbuf, unsigned short* __restrict__ kbuf,
    unsigned short* __restrict__ vtbuf) {
  __shared__ __attribute__((aligned(16))) unsigned short As[128 * 32];
  __shared__ __attribute__((aligned(16))) unsigned short Bs[128 * 32];
  int tid = threadIdx.x;
  int lane = tid & 63, w = tid >> 6;
  int wm = w >> 1, wn = w & 1;
  int lrow = lane & 15, lgrp = lane >> 4;
  int bm = blockIdx.y * 128, bn = blockIdx.x * 128;
  const unsigned short* Ab = A + (size_t)bm * Kdim;
  const unsigned short* Bb = Bt + (size_t)bn * Kdim;

  f32x4 acc[4][4] = {};
  int nk = Kdim >> 5;
  for (int kt = 0; kt < nk; ++kt) {
    int k0 = kt << 5;
    __syncthreads();
#pragma unroll
    for (int it = 0; it < 2; ++it) {
      int c = tid + it * 256;
      int row = c >> 2, kc = (c & 3) << 3;
      gload_lds16(Ab + (size_t)row * Kdim + k0 + kc, As + (size_t)c * 8);
      gload_lds16(Bb + (size_t)row * Kdim + k0 + kc, Bs + (size_t)c * 8);
    }
    __syncthreads();
    bf16x8 af[4], bfr[4];
#pragma unroll
    for (int mi = 0; mi < 4; ++mi)
      af[mi] = *reinterpret_cast<const bf16x8*>(As + (size_t)(wm * 64 + mi * 16 + lrow) * 32 + lgrp * 8);
#pragma unroll
    for (int ni = 0; ni < 4; ++ni)
      bfr[ni] = *reinterpret_cast<const bf16x8*>(Bs + (size_t)(wn * 64 + ni * 16 + lrow) * 32 + lgrp * 8);
#pragma unroll
    for (int mi = 0; mi < 4; ++mi)
#pragma unroll
      for (int ni = 0; ni < 4; ++ni)
        acc[mi][ni] = mfma16(af[mi], bfr[ni], acc[mi][ni]);
  }

  int r0 = bm + wm * 64, c0 = bn + wn * 64;
#pragma unroll
  for (int ni = 0; ni < 4; ++ni) {
    int col = c0 + ni * 16 + lrow;
    float bv = bias[col];
#pragma unroll
    for (int mi = 0; mi < 4; ++mi) {
      int rowb = r0 + mi * 16 + lgrp * 4;
      if (EPI == 2) {
        float* op = (float*)outp;
#pragma unroll
        for (int r = 0; r < 4; ++r)
          op[(size_t)(rowb + r) * Ndim + col] = acc[mi][ni][r] + bv;
      } else {
        int b = rowb >> 11, t = rowb & 2047;
        int which = col >> 10, cc = col & 1023;
        int h = cc >> 6, d = cc & 63;
        if (which == 2) {
          ushort4 pk;
          pk.x = f2bf(acc[mi][ni][0] + bv);
          pk.y = f2bf(acc[mi][ni][1] + bv);
          pk.z = f2bf(acc[mi][ni][2] + bv);
          pk.w = f2bf(acc[mi][ni][3] + bv);
          *reinterpret_cast<ushort4*>(vtbuf + ((size_t)((b * 16 + h) * 64 + d)) * T_ + t) = pk;
        } else {
          unsigned short* dst = (which == 0) ? qbuf : kbuf;
          size_t base = ((size_t)(b * 16 + h) * T_ + t) * DH_ + d;
#pragma unroll
          for (int r = 0; r < 4; ++r)
            dst[base + (size_t)r * DH_] = f2bf(acc[mi][ni][r] + bv);
        }
      }
    }
  }
}

// ---- flash attention: 4 waves x 32 q-rows, K/V tiles of 64, causal ----
__global__ __launch_bounds__(256) void attn_kernel(
    const unsigned short* __restrict__ qbuf,
    const unsigned short* __restrict__ kbuf,
    const unsigned short* __restrict__ vtbuf,
    unsigned short* __restrict__ attno) {
  __shared__ __attribute__((aligned(16))) unsigned short Ks[64 * 64];
  __shared__ __attribute__((aligned(16))) unsigned short Vts[64 * 64];
  __shared__ __attribute__((aligned(16))) unsigned short Ps[4][32 * 64];

  int tid = threadIdx.x;
  int lane = tid & 63, w = tid >> 6;
  int lrow = lane & 15, lgrp = lane >> 4;
  int qb = blockIdx.x, bh = blockIdx.y;
  int q0 = qb * 128, wq0 = q0 + w * 32;

  const unsigned short* Qb = qbuf + (size_t)bh * T_ * DH_;
  const unsigned short* Kb = kbuf + (size_t)bh * T_ * DH_;
  const unsigned short* Vb = vtbuf + (size_t)bh * DH_ * T_;

  bf16x8 qf[2][2];
#pragma unroll
  for (int mi = 0; mi < 2; ++mi)
#pragma unroll
    for (int ks = 0; ks < 2; ++ks)
      qf[mi][ks] = *reinterpret_cast<const bf16x8*>(
          Qb + (size_t)(wq0 + mi * 16 + lrow) * DH_ + ks * 32 + lgrp * 8);

  f32x4 o[2][4] = {};
  float m_run[2][4], l_run[2][4];
#pragma unroll
  for (int mi = 0; mi < 2; ++mi)
#pragma unroll
    for (int r = 0; r < 4; ++r) { m_run[mi][r] = -1e30f; l_run[mi][r] = 0.f; }

  char* pw = (char*)Ps[w];
  int nkb = qb * 2 + 2;
  for (int kb = 0; kb < nkb; ++kb) {
    __syncthreads();
#pragma unroll
    for (int it = 0; it < 2; ++it) {
      int c = tid + it * 256;
      int row = c >> 3, col16 = c & 7;
      bf16x8 kv = *reinterpret_cast<const bf16x8*>(Kb + (size_t)(kb * 64 + row) * DH_ + col16 * 8);
      bf16x8 vv = *reinterpret_cast<const bf16x8*>(Vb + (size_t)row * T_ + kb * 64 + col16 * 8);
      int off = row * 128 + ((col16 * 16) ^ ((row & 7) << 4));
      *reinterpret_cast<bf16x8*>((char*)Ks + off) = kv;
      *reinterpret_cast<bf16x8*>((char*)Vts + off) = vv;
    }
    __syncthreads();
    if (kb * 64 > wq0 + 31) continue;  // fully masked for this wave (barriers already passed)

    f32x4 s[2][4] = {};
#pragma unroll
    for (int ks = 0; ks < 2; ++ks) {
      bf16x8 kf[4];
#pragma unroll
      for (int ni = 0; ni < 4; ++ni) {
        int kr = ni * 16 + lrow;
        int off = kr * 128 + (((ks * 32 + lgrp * 8) * 2) ^ ((kr & 7) << 4));
        kf[ni] = *reinterpret_cast<const bf16x8*>((const char*)Ks + off);
      }
#pragma unroll
      for (int mi = 0; mi < 2; ++mi)
#pragma unroll
        for (int ni = 0; ni < 4; ++ni)
          s[mi][ni] = mfma16(qf[mi][ks], kf[ni], s[mi][ni]);
    }

    bool need_mask = (kb * 64 + 63 > wq0);
#pragma unroll
    for (int mi = 0; mi < 2; ++mi) {
      float alpha[4], mn[4];
#pragma unroll
      for (int r = 0; r < 4; ++r) {
        int rowq = wq0 + mi * 16 + lgrp * 4 + r;
#pragma unroll
        for (int ni = 0; ni < 4; ++ni) {
          float v = s[mi][ni][r] * 0.125f;
          if (need_mask && (kb * 64 + ni * 16 + lrow > rowq)) v = -1e30f;
          s[mi][ni][r] = v;
        }
        float pm = fmaxf(fmaxf(s[mi][0][r], s[mi][1][r]), fmaxf(s[mi][2][r], s[mi][3][r]));
#pragma unroll
        for (int dd = 1; dd < 16; dd <<= 1) pm = fmaxf(pm, __shfl_xor(pm, dd));
        float mnew = fmaxf(m_run[mi][r], pm);
        alpha[r] = __expf(m_run[mi][r] - mnew);
        mn[r] = mnew;
        m_run[mi][r] = mnew;
      }
#pragma unroll
      for (int r = 0; r < 4; ++r) {
        float rs = 0.f;
        int prow = mi * 16 + lgrp * 4 + r;
#pragma unroll
        for (int ni = 0; ni < 4; ++ni) {
          float p = __expf(s[mi][ni][r] - mn[r]);
          rs += p;
          int off = prow * 128 + ((((ni * 16 + lrow) * 2)) ^ ((prow & 7) << 4));
          *reinterpret_cast<unsigned short*>(pw + off) = f2bf(p);
        }
#pragma unroll
        for (int dd = 1; dd < 16; dd <<= 1) rs += __shfl_xor(rs, dd);
        l_run[mi][r] = l_run[mi][r] * alpha[r] + rs;
      }
#pragma unroll
      for (int di = 0; di < 4; ++di)
#pragma unroll
        for (int r = 0; r < 4; ++r)
          o[mi][di][r] *= alpha[r];
    }

    // PV: O += P @ V   (P A-frags from swizzled LDS, V B-frags from Vts)
#pragma unroll
    for (int ks = 0; ks < 2; ++ks) {
      bf16x8 pa[2], vf[4];
#pragma unroll
      for (int mi = 0; mi < 2; ++mi) {
        int prow = mi * 16 + lrow;
        int off = prow * 128 + (((ks * 32 + lgrp * 8) * 2) ^ ((prow & 7) << 4));
        pa[mi] = *reinterpret_cast<const bf16x8*>(pw + off);
      }
#pragma unroll
      for (int di = 0; di < 4; ++di) {
        int vr = di * 16 + lrow;
        int off = vr * 128 + (((ks * 32 + lgrp * 8) * 2) ^ ((vr & 7) << 4));
        vf[di] = *reinterpret_cast<const bf16x8*>((const char*)Vts + off);
      }
#pragma unroll
      for (int mi = 0; mi < 2; ++mi)
#pragma unroll
        for (int di = 0; di < 4; ++di)
          o[mi][di] = mfma16(pa[mi], vf[di], o[mi][di]);
    }
  }

  int b = bh >> 4, h = bh & 15;
#pragma unroll
  for (int mi = 0; mi < 2; ++mi) {
#pragma unroll
    for (int r = 0; r < 4; ++r) {
      float inv = 1.0f / l_run[mi][r];
      int q = wq0 + mi * 16 + lgrp * 4 + r;
      size_t base = ((size_t)(b * T_ + q)) * C_ + h * 64 + lrow;
#pragma unroll
      for (int di = 0; di < 4; ++di)
        attno[base + (size_t)di * 16] = f2bf(o[mi][di][r] * inv);
    }
  }
}

extern "C" void kernel_launch(void* const* d_in, const int* in_sizes, int n_in,
                              void* d_out, int out_size, void* d_ws, size_t ws_size,
                              hipStream_t stream) {
  const float* x      = (const float*)d_in[0];
  const float* w_qkv  = (const float*)d_in[1];
  const float* b_qkv  = (const float*)d_in[2];
  const float* w_proj = (const float*)d_in[3];
  const float* b_proj = (const float*)d_in[4];

  char* ws = (char*)d_ws;
  unsigned short* xb     = (unsigned short*)(ws + 0);          //  8 MB  x  bf16 [4096][1024]
  unsigned short* wqkvT  = (unsigned short*)(ws + 8388608);    //  6 MB  w_qkv^T bf16 [3072][1024]
  unsigned short* wprojT = (unsigned short*)(ws + 14680064);   //  2 MB  w_proj^T bf16 [1024][1024]
  unsigned short* qbuf   = (unsigned short*)(ws + 16777216);   //  8 MB  q [B,H,T,64]
  unsigned short* kbuf   = (unsigned short*)(ws + 25165824);   //  8 MB  k [B,H,T,64]
  unsigned short* vtbuf  = (unsigned short*)(ws + 33554432);   //  8 MB  v^T [B,H,64,T]
  unsigned short* attno  = (unsigned short*)(ws + 41943040);   //  8 MB  attn out bf16 [4096][1024]

  cast_kernel<<<4096, 256, 0, stream>>>(x, xb, 1048576);
  transpose_cast_kernel<<<dim3(96, 32), dim3(32, 8), 0, stream>>>(w_qkv, wqkvT, 1024, 3072);
  transpose_cast_kernel<<<dim3(32, 32), dim3(32, 8), 0, stream>>>(w_proj, wprojT, 1024, 1024);
  gemm_bt<1><<<dim3(24, 32), 256, 0, stream>>>(xb, wqkvT, b_qkv, nullptr,
                                               4096, 3072, 1024, qbuf, kbuf, vtbuf);
  attn_kernel<<<dim3(16, 32), 256, 0, stream>>>(qbuf, kbuf, vtbuf, attno);
  gemm_bt<2><<<dim3(8, 32), 256, 0, stream>>>(attno, wprojT, b_proj, d_out,
                                              4096, 1024, 1024, nullptr, nullptr, nullptr);
}

// Round 2
// 189.775 us; speedup vs baseline: 1.0306x; 1.0306x over previous
//
#include <hip/hip_runtime.h>
#include <hip/hip_bf16.h>

#define B_ 2
#define T_ 2048
#define C_ 1024
#define H_ 16
#define DH_ 64

typedef __attribute__((ext_vector_type(8))) short bf16x8;
typedef __attribute__((ext_vector_type(4))) float f32x4;

#define DEVI static __device__ __forceinline__

DEVI unsigned short f2bf(float f) {
  unsigned int u = __float_as_uint(f);
  u = (u + 0x7fffu + ((u >> 16) & 1u)) >> 16;
  return (unsigned short)u;
}

DEVI f32x4 mfma16(bf16x8 a, bf16x8 b, f32x4 c) {
  return __builtin_amdgcn_mfma_f32_16x16x32_bf16(a, b, c, 0, 0, 0);
}

DEVI void gload_lds16(const unsigned short* g, unsigned short* l) {
  __builtin_amdgcn_global_load_lds(
      (const __attribute__((address_space(1))) unsigned int*)g,
      (__attribute__((address_space(3))) unsigned int*)l, 16, 0, 0);
}

// ---- fp32 -> bf16 cast, 4 elems/thread ----
__global__ void cast_kernel(const float* __restrict__ in,
                            unsigned short* __restrict__ out, int n4) {
  int i = blockIdx.x * blockDim.x + threadIdx.x;
  if (i >= n4) return;
  float4 v = reinterpret_cast<const float4*>(in)[i];
  ushort4 o;
  o.x = f2bf(v.x); o.y = f2bf(v.y); o.z = f2bf(v.z); o.w = f2bf(v.w);
  reinterpret_cast<ushort4*>(out)[i] = o;
}

// ---- transpose + cast: in[R][C] fp32 -> out[C][R] bf16 ----
__global__ void transpose_cast_kernel(const float* __restrict__ in,
                                      unsigned short* __restrict__ out,
                                      int R, int C) {
  __shared__ float tile[32][33];
  int c0 = blockIdx.x * 32, r0 = blockIdx.y * 32;
  int tx = threadIdx.x, ty = threadIdx.y;
#pragma unroll
  for (int j = 0; j < 32; j += 8)
    tile[ty + j][tx] = in[(size_t)(r0 + ty + j) * C + c0 + tx];
  __syncthreads();
#pragma unroll
  for (int j = 0; j < 32; j += 8)
    out[(size_t)(c0 + ty + j) * R + r0 + tx] = f2bf(tile[tx][ty + j]);
}

// ---- GEMM C[M,N] = A[M,K] @ Bt[N,K]^T + bias  (m97 structure) ----
template <int EPI>
__global__ __launch_bounds__(256) void gemm_bt(
    const unsigned short* __restrict__ A, const unsigned short* __restrict__ Bt,
    const float* __restrict__ bias, void* __restrict__ outp,
    int Mdim, int Ndim, int Kdim,
    unsigned short* __restrict__ qbuf, unsigned short* __restrict__ kbuf,
    unsigned short* __restrict__ vtbuf) {
  __shared__ __attribute__((aligned(16))) unsigned short As[128 * 32];
  __shared__ __attribute__((aligned(16))) unsigned short Bs[128 * 32];
  int tid = threadIdx.x;
  int lane = tid & 63, w = tid >> 6;
  int wm = w >> 1, wn = w & 1;
  int lrow = lane & 15, lgrp = lane >> 4;
  int bm = blockIdx.y * 128, bn = blockIdx.x * 128;
  const unsigned short* Ab = A + (size_t)bm * Kdim;
  const unsigned short* Bb = Bt + (size_t)bn * Kdim;

  f32x4 acc[4][4] = {};
  int nk = Kdim >> 5;
  for (int kt = 0; kt < nk; ++kt) {
    int k0 = kt << 5;
    __syncthreads();
#pragma unroll
    for (int it = 0; it < 2; ++it) {
      int c = tid + it * 256;
      int row = c >> 2, kc = (c & 3) << 3;
      gload_lds16(Ab + (size_t)row * Kdim + k0 + kc, As + (size_t)c * 8);
      gload_lds16(Bb + (size_t)row * Kdim + k0 + kc, Bs + (size_t)c * 8);
    }
    __syncthreads();
    bf16x8 af[4], bfr[4];
#pragma unroll
    for (int mi = 0; mi < 4; ++mi)
      af[mi] = *reinterpret_cast<const bf16x8*>(As + (size_t)(wm * 64 + mi * 16 + lrow) * 32 + lgrp * 8);
#pragma unroll
    for (int ni = 0; ni < 4; ++ni)
      bfr[ni] = *reinterpret_cast<const bf16x8*>(Bs + (size_t)(wn * 64 + ni * 16 + lrow) * 32 + lgrp * 8);
#pragma unroll
    for (int mi = 0; mi < 4; ++mi)
#pragma unroll
      for (int ni = 0; ni < 4; ++ni)
        acc[mi][ni] = mfma16(af[mi], bfr[ni], acc[mi][ni]);
  }

  int r0 = bm + wm * 64, c0 = bn + wn * 64;
#pragma unroll
  for (int ni = 0; ni < 4; ++ni) {
    int col = c0 + ni * 16 + lrow;
    float bv = bias[col];
#pragma unroll
    for (int mi = 0; mi < 4; ++mi) {
      int rowb = r0 + mi * 16 + lgrp * 4;
      if (EPI == 2) {
        float* op = (float*)outp;
#pragma unroll
        for (int r = 0; r < 4; ++r)
          op[(size_t)(rowb + r) * Ndim + col] = acc[mi][ni][r] + bv;
      } else {
        int b = rowb >> 11, t = rowb & 2047;
        int which = col >> 10, cc = col & 1023;
        int h = cc >> 6, d = cc & 63;
        if (which == 2) {
          ushort4 pk;
          pk.x = f2bf(acc[mi][ni][0] + bv);
          pk.y = f2bf(acc[mi][ni][1] + bv);
          pk.z = f2bf(acc[mi][ni][2] + bv);
          pk.w = f2bf(acc[mi][ni][3] + bv);
          *reinterpret_cast<ushort4*>(vtbuf + ((size_t)((b * 16 + h) * 64 + d)) * T_ + t) = pk;
        } else {
          unsigned short* dst = (which == 0) ? qbuf : kbuf;
          size_t base = ((size_t)(b * 16 + h) * T_ + t) * DH_ + d;
#pragma unroll
          for (int r = 0; r < 4; ++r)
            dst[base + (size_t)r * DH_] = f2bf(acc[mi][ni][r] + bv);
        }
      }
    }
  }
}

// ---- flash attention: causal-folded blocks (qb, 15-qb), double-buffered K/V ----
// grid (8, 32): block b does q-tiles {b, 15-b} -> exactly 34 kv-iters per block.
__global__ __launch_bounds__(256) void attn_kernel(
    const unsigned short* __restrict__ qbuf,
    const unsigned short* __restrict__ kbuf,
    const unsigned short* __restrict__ vtbuf,
    unsigned short* __restrict__ attno) {
  __shared__ __attribute__((aligned(16))) unsigned short Ks[2][64 * 64];
  __shared__ __attribute__((aligned(16))) unsigned short Vts[2][64 * 64];
  __shared__ __attribute__((aligned(16))) unsigned short Ps[4][32 * 64];

  int tid = threadIdx.x;
  int lane = tid & 63, w = tid >> 6;
  int lrow = lane & 15, lgrp = lane >> 4;
  int bh = blockIdx.y;

  const unsigned short* Qb = qbuf + (size_t)bh * T_ * DH_;
  const unsigned short* Kb = kbuf + (size_t)bh * T_ * DH_;
  const unsigned short* Vb = vtbuf + (size_t)bh * DH_ * T_;

  // staging geometry: 512 chunks of 16B over 2 per-thread iterations
  int srow0 = tid >> 3, scol = tid & 7;
  int srow1 = srow0 + 32;
  int soff0 = srow0 * 128 + ((scol * 16) ^ ((srow0 & 7) << 4));
  int soff1 = srow1 * 128 + ((scol * 16) ^ ((srow1 & 7) << 4));
  char* pw = (char*)Ps[w];
  const float SC = 0.125f * 1.44269504f;  // scale * log2(e): softmax in exp2 domain

  bf16x8 sk0, sk1, sv0, sv1;
  auto stage_load = [&](int kb) {
    sk0 = *reinterpret_cast<const bf16x8*>(Kb + (size_t)(kb * 64 + srow0) * DH_ + scol * 8);
    sk1 = *reinterpret_cast<const bf16x8*>(Kb + (size_t)(kb * 64 + srow1) * DH_ + scol * 8);
    sv0 = *reinterpret_cast<const bf16x8*>(Vb + (size_t)srow0 * T_ + kb * 64 + scol * 8);
    sv1 = *reinterpret_cast<const bf16x8*>(Vb + (size_t)srow1 * T_ + kb * 64 + scol * 8);
  };
  auto stage_write = [&](int buf) {
    char* kbase = (char*)Ks[buf];
    char* vbase = (char*)Vts[buf];
    *reinterpret_cast<bf16x8*>(kbase + soff0) = sk0;
    *reinterpret_cast<bf16x8*>(kbase + soff1) = sk1;
    *reinterpret_cast<bf16x8*>(vbase + soff0) = sv0;
    *reinterpret_cast<bf16x8*>(vbase + soff1) = sv1;
  };

#pragma unroll 1
  for (int ph = 0; ph < 2; ++ph) {
    int qb = ph ? (15 - blockIdx.x) : blockIdx.x;
    int wq0 = qb * 128 + w * 32;
    int nkb = qb * 2 + 2;

    bf16x8 qf[2][2];
#pragma unroll
    for (int mi = 0; mi < 2; ++mi)
#pragma unroll
      for (int ks = 0; ks < 2; ++ks)
        qf[mi][ks] = *reinterpret_cast<const bf16x8*>(
            Qb + (size_t)(wq0 + mi * 16 + lrow) * DH_ + ks * 32 + lgrp * 8);

    f32x4 o[2][4] = {};
    float m_run[2][4], l_run[2][4];
#pragma unroll
    for (int mi = 0; mi < 2; ++mi)
#pragma unroll
      for (int r = 0; r < 4; ++r) { m_run[mi][r] = -1e30f; l_run[mi][r] = 0.f; }

    __syncthreads();  // prev phase done reading LDS before we overwrite buf 0
    stage_load(0);
    stage_write(0);
    int cur = 0;

#pragma unroll 1
    for (int kb = 0; kb < nkb; ++kb) {
      __syncthreads();  // staged writes visible; prev iter reads done
      bool have_next = (kb + 1 < nkb);
      if (have_next) stage_load(kb + 1);  // HBM/L2 latency hides under compute

      if (kb * 64 <= wq0 + 31) {
        const char* kbase = (const char*)Ks[cur];
        const char* vbase = (const char*)Vts[cur];

        f32x4 s[2][4] = {};
#pragma unroll
        for (int ks = 0; ks < 2; ++ks) {
          bf16x8 kf[4];
#pragma unroll
          for (int ni = 0; ni < 4; ++ni) {
            int kr = ni * 16 + lrow;
            int off = kr * 128 + (((ks * 32 + lgrp * 8) * 2) ^ ((kr & 7) << 4));
            kf[ni] = *reinterpret_cast<const bf16x8*>(kbase + off);
          }
#pragma unroll
          for (int mi = 0; mi < 2; ++mi)
#pragma unroll
            for (int ni = 0; ni < 4; ++ni)
              s[mi][ni] = mfma16(qf[mi][ks], kf[ni], s[mi][ni]);
        }

        bool need_mask = (kb * 64 + 63 > wq0);
#pragma unroll
        for (int mi = 0; mi < 2; ++mi) {
          float alpha[4], mn[4];
#pragma unroll
          for (int r = 0; r < 4; ++r) {
            int rowq = wq0 + mi * 16 + lgrp * 4 + r;
#pragma unroll
            for (int ni = 0; ni < 4; ++ni) {
              float v = s[mi][ni][r] * SC;
              if (need_mask && (kb * 64 + ni * 16 + lrow > rowq)) v = -1e30f;
              s[mi][ni][r] = v;
            }
            float pm = fmaxf(fmaxf(s[mi][0][r], s[mi][1][r]), fmaxf(s[mi][2][r], s[mi][3][r]));
#pragma unroll
            for (int dd = 1; dd < 16; dd <<= 1) pm = fmaxf(pm, __shfl_xor(pm, dd));
            float mnew = fmaxf(m_run[mi][r], pm);
            alpha[r] = exp2f(m_run[mi][r] - mnew);
            mn[r] = mnew;
            m_run[mi][r] = mnew;
          }
#pragma unroll
          for (int r = 0; r < 4; ++r) {
            float rs = 0.f;
            int prow = mi * 16 + lgrp * 4 + r;
#pragma unroll
            for (int ni = 0; ni < 4; ++ni) {
              float p = exp2f(s[mi][ni][r] - mn[r]);
              rs += p;
              int off = prow * 128 + ((((ni * 16 + lrow) * 2)) ^ ((prow & 7) << 4));
              *reinterpret_cast<unsigned short*>(pw + off) = f2bf(p);
            }
#pragma unroll
            for (int dd = 1; dd < 16; dd <<= 1) rs += __shfl_xor(rs, dd);
            l_run[mi][r] = l_run[mi][r] * alpha[r] + rs;
          }
#pragma unroll
          for (int di = 0; di < 4; ++di)
#pragma unroll
            for (int r = 0; r < 4; ++r)
              o[mi][di][r] *= alpha[r];
        }

        // PV: O += P @ V
#pragma unroll
        for (int ks = 0; ks < 2; ++ks) {
          bf16x8 pa[2], vf[4];
#pragma unroll
          for (int mi = 0; mi < 2; ++mi) {
            int prow = mi * 16 + lrow;
            int off = prow * 128 + (((ks * 32 + lgrp * 8) * 2) ^ ((prow & 7) << 4));
            pa[mi] = *reinterpret_cast<const bf16x8*>(pw + off);
          }
#pragma unroll
          for (int di = 0; di < 4; ++di) {
            int vr = di * 16 + lrow;
            int off = vr * 128 + (((ks * 32 + lgrp * 8) * 2) ^ ((vr & 7) << 4));
            vf[di] = *reinterpret_cast<const bf16x8*>(vbase + off);
          }
#pragma unroll
          for (int mi = 0; mi < 2; ++mi)
#pragma unroll
            for (int di = 0; di < 4; ++di)
              o[mi][di] = mfma16(pa[mi], vf[di], o[mi][di]);
        }
      }

      if (have_next) stage_write(cur ^ 1);  // waits vmcnt, fills other buffer
      cur ^= 1;
    }

    int b = bh >> 4, h = bh & 15;
#pragma unroll
    for (int mi = 0; mi < 2; ++mi) {
#pragma unroll
      for (int r = 0; r < 4; ++r) {
        float inv = 1.0f / l_run[mi][r];
        int q = wq0 + mi * 16 + lgrp * 4 + r;
        size_t base = ((size_t)(b * T_ + q)) * C_ + h * 64 + lrow;
#pragma unroll
        for (int di = 0; di < 4; ++di)
          attno[base + (size_t)di * 16] = f2bf(o[mi][di][r] * inv);
      }
    }
  }
}

extern "C" void kernel_launch(void* const* d_in, const int* in_sizes, int n_in,
                              void* d_out, int out_size, void* d_ws, size_t ws_size,
                              hipStream_t stream) {
  const float* x      = (const float*)d_in[0];
  const float* w_qkv  = (const float*)d_in[1];
  const float* b_qkv  = (const float*)d_in[2];
  const float* w_proj = (const float*)d_in[3];
  const float* b_proj = (const float*)d_in[4];

  char* ws = (char*)d_ws;
  unsigned short* xb     = (unsigned short*)(ws + 0);          //  8 MB  x  bf16 [4096][1024]
  unsigned short* wqkvT  = (unsigned short*)(ws + 8388608);    //  6 MB  w_qkv^T bf16 [3072][1024]
  unsigned short* wprojT = (unsigned short*)(ws + 14680064);   //  2 MB  w_proj^T bf16 [1024][1024]
  unsigned short* qbuf   = (unsigned short*)(ws + 16777216);   //  8 MB  q [B,H,T,64]
  unsigned short* kbuf   = (unsigned short*)(ws + 25165824);   //  8 MB  k [B,H,T,64]
  unsigned short* vtbuf  = (unsigned short*)(ws + 33554432);   //  8 MB  v^T [B,H,64,T]
  unsigned short* attno  = (unsigned short*)(ws + 41943040);   //  8 MB  attn out bf16 [4096][1024]

  cast_kernel<<<4096, 256, 0, stream>>>(x, xb, 1048576);
  transpose_cast_kernel<<<dim3(96, 32), dim3(32, 8), 0, stream>>>(w_qkv, wqkvT, 1024, 3072);
  transpose_cast_kernel<<<dim3(32, 32), dim3(32, 8), 0, stream>>>(w_proj, wprojT, 1024, 1024);
  gemm_bt<1><<<dim3(24, 32), 256, 0, stream>>>(xb, wqkvT, b_qkv, nullptr,
                                               4096, 3072, 1024, qbuf, kbuf, vtbuf);
  attn_kernel<<<dim3(8, 32), 256, 0, stream>>>(qbuf, kbuf, vtbuf, attno);
  gemm_bt<2><<<dim3(8, 32), 256, 0, stream>>>(attno, wprojT, b_proj, d_out,
                                              4096, 1024, 1024, nullptr, nullptr, nullptr);
}

// Round 3
// 144.176 us; speedup vs baseline: 1.3565x; 1.3163x over previous
//
#include <hip/hip_runtime.h>
#include <hip/hip_bf16.h>

#define B_ 2
#define T_ 2048
#define C_ 1024
#define H_ 16
#define DH_ 64

typedef __attribute__((ext_vector_type(8))) short bf16x8;
typedef __attribute__((ext_vector_type(4))) float f32x4;

#define DEVI static __device__ __forceinline__

DEVI unsigned short f2bf(float f) {
  unsigned int u = __float_as_uint(f);
  u = (u + 0x7fffu + ((u >> 16) & 1u)) >> 16;
  return (unsigned short)u;
}

DEVI f32x4 mfma16(bf16x8 a, bf16x8 b, f32x4 c) {
  return __builtin_amdgcn_mfma_f32_16x16x32_bf16(a, b, c, 0, 0, 0);
}

DEVI void gload_lds16(const unsigned short* g, unsigned short* l) {
  __builtin_amdgcn_global_load_lds(
      (const __attribute__((address_space(1))) unsigned int*)g,
      (__attribute__((address_space(3))) unsigned int*)l, 16, 0, 0);
}

// ---- fp32 -> bf16 cast, 4 elems/thread ----
__global__ void cast_kernel(const float* __restrict__ in,
                            unsigned short* __restrict__ out, int n4) {
  int i = blockIdx.x * blockDim.x + threadIdx.x;
  if (i >= n4) return;
  float4 v = reinterpret_cast<const float4*>(in)[i];
  ushort4 o;
  o.x = f2bf(v.x); o.y = f2bf(v.y); o.z = f2bf(v.z); o.w = f2bf(v.w);
  reinterpret_cast<ushort4*>(out)[i] = o;
}

// ---- transpose + cast: in[R][C] fp32 -> out[C][R] bf16 ----
__global__ void transpose_cast_kernel(const float* __restrict__ in,
                                      unsigned short* __restrict__ out,
                                      int R, int C) {
  __shared__ float tile[32][33];
  int c0 = blockIdx.x * 32, r0 = blockIdx.y * 32;
  int tx = threadIdx.x, ty = threadIdx.y;
#pragma unroll
  for (int j = 0; j < 32; j += 8)
    tile[ty + j][tx] = in[(size_t)(r0 + ty + j) * C + c0 + tx];
  __syncthreads();
#pragma unroll
  for (int j = 0; j < 32; j += 8)
    out[(size_t)(c0 + ty + j) * R + r0 + tx] = f2bf(tile[tx][ty + j]);
}

// ---- GEMM C[M,N] = A[M,K] @ Bt[N,K]^T + bias  (m97 structure) ----
template <int EPI>
__global__ __launch_bounds__(256) void gemm_bt(
    const unsigned short* __restrict__ A, const unsigned short* __restrict__ Bt,
    const float* __restrict__ bias, void* __restrict__ outp,
    int Mdim, int Ndim, int Kdim,
    unsigned short* __restrict__ qbuf, unsigned short* __restrict__ kbuf,
    unsigned short* __restrict__ vtbuf) {
  __shared__ __attribute__((aligned(16))) unsigned short As[128 * 32];
  __shared__ __attribute__((aligned(16))) unsigned short Bs[128 * 32];
  int tid = threadIdx.x;
  int lane = tid & 63, w = tid >> 6;
  int wm = w >> 1, wn = w & 1;
  int lrow = lane & 15, lgrp = lane >> 4;
  int bm = blockIdx.y * 128, bn = blockIdx.x * 128;
  const unsigned short* Ab = A + (size_t)bm * Kdim;
  const unsigned short* Bb = Bt + (size_t)bn * Kdim;

  f32x4 acc[4][4] = {};
  int nk = Kdim >> 5;
  for (int kt = 0; kt < nk; ++kt) {
    int k0 = kt << 5;
    __syncthreads();
#pragma unroll
    for (int it = 0; it < 2; ++it) {
      int c = tid + it * 256;
      int row = c >> 2, kc = (c & 3) << 3;
      gload_lds16(Ab + (size_t)row * Kdim + k0 + kc, As + (size_t)c * 8);
      gload_lds16(Bb + (size_t)row * Kdim + k0 + kc, Bs + (size_t)c * 8);
    }
    __syncthreads();
    bf16x8 af[4], bfr[4];
#pragma unroll
    for (int mi = 0; mi < 4; ++mi)
      af[mi] = *reinterpret_cast<const bf16x8*>(As + (size_t)(wm * 64 + mi * 16 + lrow) * 32 + lgrp * 8);
#pragma unroll
    for (int ni = 0; ni < 4; ++ni)
      bfr[ni] = *reinterpret_cast<const bf16x8*>(Bs + (size_t)(wn * 64 + ni * 16 + lrow) * 32 + lgrp * 8);
#pragma unroll
    for (int mi = 0; mi < 4; ++mi)
#pragma unroll
      for (int ni = 0; ni < 4; ++ni)
        acc[mi][ni] = mfma16(af[mi], bfr[ni], acc[mi][ni]);
  }

  int r0 = bm + wm * 64, c0 = bn + wn * 64;
#pragma unroll
  for (int ni = 0; ni < 4; ++ni) {
    int col = c0 + ni * 16 + lrow;
    float bv = bias[col];
#pragma unroll
    for (int mi = 0; mi < 4; ++mi) {
      int rowb = r0 + mi * 16 + lgrp * 4;
      if (EPI == 2) {
        float* op = (float*)outp;
#pragma unroll
        for (int r = 0; r < 4; ++r)
          op[(size_t)(rowb + r) * Ndim + col] = acc[mi][ni][r] + bv;
      } else {
        int b = rowb >> 11, t = rowb & 2047;
        int which = col >> 10, cc = col & 1023;
        int h = cc >> 6, d = cc & 63;
        if (which == 2) {
          ushort4 pk;
          pk.x = f2bf(acc[mi][ni][0] + bv);
          pk.y = f2bf(acc[mi][ni][1] + bv);
          pk.z = f2bf(acc[mi][ni][2] + bv);
          pk.w = f2bf(acc[mi][ni][3] + bv);
          *reinterpret_cast<ushort4*>(vtbuf + ((size_t)((b * 16 + h) * 64 + d)) * T_ + t) = pk;
        } else {
          unsigned short* dst = (which == 0) ? qbuf : kbuf;
          size_t base = ((size_t)(b * 16 + h) * T_ + t) * DH_ + d;
#pragma unroll
          for (int r = 0; r < 4; ++r)
            dst[base + (size_t)r * DH_] = f2bf(acc[mi][ni][r] + bv);
        }
      }
    }
  }
}

// ---- flash attention: one 64-row q-tile per block, 4 waves x 16 rows ----
// grid = 1024 flat. CU-mates (g, g+256, g+512, g+768) get complementary tile
// sizes {p+1, 32-p, p+9, 24-p} = 66 kv-iters per CU (uniform). bh in low bits
// of g so each XCD touches only 4 heads (KV fits its 4MB L2).
__global__ __launch_bounds__(256, 4) void attn_kernel(
    const unsigned short* __restrict__ qbuf,
    const unsigned short* __restrict__ kbuf,
    const unsigned short* __restrict__ vtbuf,
    unsigned short* __restrict__ attno) {
  __shared__ __attribute__((aligned(16))) unsigned short Ks[64 * 64];
  __shared__ __attribute__((aligned(16))) unsigned short Vts[64 * 64];
  __shared__ __attribute__((aligned(16))) unsigned short Ps[4][16 * 64];

  int tid = threadIdx.x;
  int lane = tid & 63, w = tid >> 6;
  int lrow = lane & 15, lgrp = lane >> 4;

  int g = blockIdx.x;
  int s = g >> 8;                                 // CU-mate slot
  int p = (g >> 3) & 7;
  int bh = (g & 7) | (((g >> 6) & 3) << 3);       // head: low bits -> XCD locality
  int qb = (s == 0) ? p : (s == 1) ? (31 - p) : (s == 2) ? (8 + p) : (23 - p);
  int wq0 = qb * 64 + w * 16;
  int nkb = qb + 1;

  const unsigned short* Qb = qbuf + (size_t)bh * T_ * DH_;
  const unsigned short* Kb = kbuf + (size_t)bh * T_ * DH_;
  const unsigned short* Vb = vtbuf + (size_t)bh * DH_ * T_;

  // staging geometry: 512 chunks of 16B over 2 per-thread stores
  int srow0 = tid >> 3, scol = tid & 7;
  int srow1 = srow0 + 32;
  int soff0 = srow0 * 128 + ((scol * 16) ^ ((srow0 & 7) << 4));
  int soff1 = srow1 * 128 + ((scol * 16) ^ ((srow1 & 7) << 4));
  char* pw = (char*)Ps[w];
  const float SC = 0.125f * 1.44269504f;  // scale * log2(e)

  bf16x8 qf[2];
#pragma unroll
  for (int ks = 0; ks < 2; ++ks)
    qf[ks] = *reinterpret_cast<const bf16x8*>(
        Qb + (size_t)(wq0 + lrow) * DH_ + ks * 32 + lgrp * 8);

  f32x4 o[4] = {};
  float m_run[4], l_run[4];
#pragma unroll
  for (int r = 0; r < 4; ++r) { m_run[r] = -1e30f; l_run[r] = 0.f; }

  bf16x8 sk0, sk1, sv0, sv1;
  auto stage_load = [&](int kb) {
    sk0 = *reinterpret_cast<const bf16x8*>(Kb + (size_t)(kb * 64 + srow0) * DH_ + scol * 8);
    sk1 = *reinterpret_cast<const bf16x8*>(Kb + (size_t)(kb * 64 + srow1) * DH_ + scol * 8);
    sv0 = *reinterpret_cast<const bf16x8*>(Vb + (size_t)srow0 * T_ + kb * 64 + scol * 8);
    sv1 = *reinterpret_cast<const bf16x8*>(Vb + (size_t)srow1 * T_ + kb * 64 + scol * 8);
  };
  auto stage_write = [&]() {
    *reinterpret_cast<bf16x8*>((char*)Ks + soff0) = sk0;
    *reinterpret_cast<bf16x8*>((char*)Ks + soff1) = sk1;
    *reinterpret_cast<bf16x8*>((char*)Vts + soff0) = sv0;
    *reinterpret_cast<bf16x8*>((char*)Vts + soff1) = sv1;
  };

  stage_load(0);
#pragma unroll 1
  for (int kb = 0; kb < nkb; ++kb) {
    if (kb > 0) __syncthreads();   // prev iter's LDS reads done
    stage_write();
    __syncthreads();               // staged K/V visible
    if (kb + 1 < nkb) stage_load(kb + 1);  // HBM/L2 latency hides under compute

    // QK^T for this wave's 16 rows
    f32x4 sreg[4] = {};
#pragma unroll
    for (int ks = 0; ks < 2; ++ks) {
      bf16x8 kf[4];
#pragma unroll
      for (int ni = 0; ni < 4; ++ni) {
        int kr = ni * 16 + lrow;
        int off = kr * 128 + (((ks * 32 + lgrp * 8) * 2) ^ ((kr & 7) << 4));
        kf[ni] = *reinterpret_cast<const bf16x8*>((const char*)Ks + off);
      }
#pragma unroll
      for (int ni = 0; ni < 4; ++ni)
        sreg[ni] = mfma16(qf[ks], kf[ni], sreg[ni]);
    }

    bool need_mask = (kb == qb);
    float alpha[4], mn[4];
#pragma unroll
    for (int r = 0; r < 4; ++r) {
      int rowq = wq0 + lgrp * 4 + r;
#pragma unroll
      for (int ni = 0; ni < 4; ++ni) {
        float v = sreg[ni][r] * SC;
        if (need_mask && (kb * 64 + ni * 16 + lrow > rowq)) v = -1e30f;
        sreg[ni][r] = v;
      }
      float pm = fmaxf(fmaxf(sreg[0][r], sreg[1][r]), fmaxf(sreg[2][r], sreg[3][r]));
#pragma unroll
      for (int dd = 1; dd < 16; dd <<= 1) pm = fmaxf(pm, __shfl_xor(pm, dd));
      float mnew = fmaxf(m_run[r], pm);
      alpha[r] = exp2f(m_run[r] - mnew);
      mn[r] = mnew;
      m_run[r] = mnew;
    }
#pragma unroll
    for (int r = 0; r < 4; ++r) {
      float rs = 0.f;
      int prow = lgrp * 4 + r;
#pragma unroll
      for (int ni = 0; ni < 4; ++ni) {
        float pe = exp2f(sreg[ni][r] - mn[r]);
        rs += pe;
        int off = prow * 128 + ((((ni * 16 + lrow) * 2)) ^ ((prow & 7) << 4));
        *reinterpret_cast<unsigned short*>(pw + off) = f2bf(pe);
      }
#pragma unroll
      for (int dd = 1; dd < 16; dd <<= 1) rs += __shfl_xor(rs, dd);
      l_run[r] = l_run[r] * alpha[r] + rs;
    }
#pragma unroll
    for (int di = 0; di < 4; ++di)
#pragma unroll
      for (int r = 0; r < 4; ++r)
        o[di][r] *= alpha[r];

    // PV: O += P @ V
#pragma unroll
    for (int ks = 0; ks < 2; ++ks) {
      bf16x8 pa, vf[4];
      {
        int off = lrow * 128 + (((ks * 32 + lgrp * 8) * 2) ^ ((lrow & 7) << 4));
        pa = *reinterpret_cast<const bf16x8*>(pw + off);
      }
#pragma unroll
      for (int di = 0; di < 4; ++di) {
        int vr = di * 16 + lrow;
        int off = vr * 128 + (((ks * 32 + lgrp * 8) * 2) ^ ((vr & 7) << 4));
        vf[di] = *reinterpret_cast<const bf16x8*>((const char*)Vts + off);
      }
#pragma unroll
      for (int di = 0; di < 4; ++di)
        o[di] = mfma16(pa, vf[di], o[di]);
    }
  }

  int b = bh >> 4, h = bh & 15;
#pragma unroll
  for (int r = 0; r < 4; ++r) {
    float inv = 1.0f / l_run[r];
    int q = wq0 + lgrp * 4 + r;
    size_t base = ((size_t)(b * T_ + q)) * C_ + h * 64 + lrow;
#pragma unroll
    for (int di = 0; di < 4; ++di)
      attno[base + (size_t)di * 16] = f2bf(o[di][r] * inv);
  }
}

extern "C" void kernel_launch(void* const* d_in, const int* in_sizes, int n_in,
                              void* d_out, int out_size, void* d_ws, size_t ws_size,
                              hipStream_t stream) {
  const float* x      = (const float*)d_in[0];
  const float* w_qkv  = (const float*)d_in[1];
  const float* b_qkv  = (const float*)d_in[2];
  const float* w_proj = (const float*)d_in[3];
  const float* b_proj = (const float*)d_in[4];

  char* ws = (char*)d_ws;
  unsigned short* xb     = (unsigned short*)(ws + 0);          //  8 MB  x  bf16 [4096][1024]
  unsigned short* wqkvT  = (unsigned short*)(ws + 8388608);    //  6 MB  w_qkv^T bf16 [3072][1024]
  unsigned short* wprojT = (unsigned short*)(ws + 14680064);   //  2 MB  w_proj^T bf16 [1024][1024]
  unsigned short* qbuf   = (unsigned short*)(ws + 16777216);   //  8 MB  q [B,H,T,64]
  unsigned short* kbuf   = (unsigned short*)(ws + 25165824);   //  8 MB  k [B,H,T,64]
  unsigned short* vtbuf  = (unsigned short*)(ws + 33554432);   //  8 MB  v^T [B,H,64,T]
  unsigned short* attno  = (unsigned short*)(ws + 41943040);   //  8 MB  attn out bf16 [4096][1024]

  cast_kernel<<<4096, 256, 0, stream>>>(x, xb, 1048576);
  transpose_cast_kernel<<<dim3(96, 32), dim3(32, 8), 0, stream>>>(w_qkv, wqkvT, 1024, 3072);
  transpose_cast_kernel<<<dim3(32, 32), dim3(32, 8), 0, stream>>>(w_proj, wprojT, 1024, 1024);
  gemm_bt<1><<<dim3(24, 32), 256, 0, stream>>>(xb, wqkvT, b_qkv, nullptr,
                                               4096, 3072, 1024, qbuf, kbuf, vtbuf);
  attn_kernel<<<dim3(1024), 256, 0, stream>>>(qbuf, kbuf, vtbuf, attno);
  gemm_bt<2><<<dim3(8, 32), 256, 0, stream>>>(attno, wprojT, b_proj, d_out,
                                              4096, 1024, 1024, nullptr, nullptr, nullptr);
}

// Round 4
// 117.263 us; speedup vs baseline: 1.6678x; 1.2295x over previous
//
#include <hip/hip_runtime.h>
#include <hip/hip_bf16.h>

#define B_ 2
#define T_ 2048
#define C_ 1024
#define H_ 16
#define DH_ 64

typedef __attribute__((ext_vector_type(8))) short bf16x8;
typedef __attribute__((ext_vector_type(4))) float f32x4;
typedef __attribute__((ext_vector_type(4))) unsigned int u32x4;

#define DEVI static __device__ __forceinline__

DEVI unsigned short f2bf(float f) {
  unsigned int u = __float_as_uint(f);
  u = (u + 0x7fffu + ((u >> 16) & 1u)) >> 16;
  return (unsigned short)u;
}

DEVI f32x4 mfma16(bf16x8 a, bf16x8 b, f32x4 c) {
  return __builtin_amdgcn_mfma_f32_16x16x32_bf16(a, b, c, 0, 0, 0);
}

DEVI void gload_lds16(const unsigned short* g, unsigned short* l) {
  __builtin_amdgcn_global_load_lds(
      (const __attribute__((address_space(1))) unsigned int*)g,
      (__attribute__((address_space(3))) unsigned int*)l, 16, 0, 0);
}

DEVI unsigned int cvtpk_bf16(float lo, float hi) {
  unsigned int r;
  asm("v_cvt_pk_bf16_f32 %0, %1, %2" : "=v"(r) : "v"(lo), "v"(hi));
  return r;
}

DEVI f32x4 vmax4(f32x4 a, f32x4 b) {
  f32x4 r;
  r[0] = fmaxf(a[0], b[0]); r[1] = fmaxf(a[1], b[1]);
  r[2] = fmaxf(a[2], b[2]); r[3] = fmaxf(a[3], b[3]);
  return r;
}

// K-row permutation: LDS row for kv so that lane-group g's S^T registers hold
// kv chunks {g-block, g-block+16} (makes permlane32_swap the exact exchange).
DEVI int kperm(int kv) {
  return (kv & 3) | (((kv >> 3) & 1) << 2) | (((kv >> 5) & 1) << 3) |
         (((kv >> 2) & 1) << 4) | (((kv >> 4) & 1) << 5);
}

// ---- fp32 -> bf16 cast ----
__global__ void cast_kernel(const float* __restrict__ in,
                            unsigned short* __restrict__ out, int n4) {
  int i = blockIdx.x * blockDim.x + threadIdx.x;
  if (i >= n4) return;
  float4 v = reinterpret_cast<const float4*>(in)[i];
  ushort4 o;
  o.x = f2bf(v.x); o.y = f2bf(v.y); o.z = f2bf(v.z); o.w = f2bf(v.w);
  reinterpret_cast<ushort4*>(out)[i] = o;
}

// ---- transpose + cast: in[R][C] fp32 -> out[C][R] bf16 ----
__global__ void transpose_cast_kernel(const float* __restrict__ in,
                                      unsigned short* __restrict__ out,
                                      int R, int C) {
  __shared__ float tile[32][33];
  int c0 = blockIdx.x * 32, r0 = blockIdx.y * 32;
  int tx = threadIdx.x, ty = threadIdx.y;
#pragma unroll
  for (int j = 0; j < 32; j += 8)
    tile[ty + j][tx] = in[(size_t)(r0 + ty + j) * C + c0 + tx];
  __syncthreads();
#pragma unroll
  for (int j = 0; j < 32; j += 8)
    out[(size_t)(c0 + ty + j) * R + r0 + tx] = f2bf(tile[tx][ty + j]);
}

// ---- GEMM C[M,N] = A[M,K] @ Bt[N,K]^T + bias  (m97 structure) ----
template <int EPI>
__global__ __launch_bounds__(256) void gemm_bt(
    const unsigned short* __restrict__ A, const unsigned short* __restrict__ Bt,
    const float* __restrict__ bias, void* __restrict__ outp,
    int Mdim, int Ndim, int Kdim,
    unsigned short* __restrict__ qbuf, unsigned short* __restrict__ kbuf,
    unsigned short* __restrict__ vtbuf) {
  __shared__ __attribute__((aligned(16))) unsigned short As[128 * 32];
  __shared__ __attribute__((aligned(16))) unsigned short Bs[128 * 32];
  int tid = threadIdx.x;
  int lane = tid & 63, w = tid >> 6;
  int wm = w >> 1, wn = w & 1;
  int lrow = lane & 15, lgrp = lane >> 4;
  int bm = blockIdx.y * 128, bn = blockIdx.x * 128;
  const unsigned short* Ab = A + (size_t)bm * Kdim;
  const unsigned short* Bb = Bt + (size_t)bn * Kdim;

  f32x4 acc[4][4] = {};
  int nk = Kdim >> 5;
  for (int kt = 0; kt < nk; ++kt) {
    int k0 = kt << 5;
    __syncthreads();
#pragma unroll
    for (int it = 0; it < 2; ++it) {
      int c = tid + it * 256;
      int row = c >> 2, kc = (c & 3) << 3;
      gload_lds16(Ab + (size_t)row * Kdim + k0 + kc, As + (size_t)c * 8);
      gload_lds16(Bb + (size_t)row * Kdim + k0 + kc, Bs + (size_t)c * 8);
    }
    __syncthreads();
    bf16x8 af[4], bfr[4];
#pragma unroll
    for (int mi = 0; mi < 4; ++mi)
      af[mi] = *reinterpret_cast<const bf16x8*>(As + (size_t)(wm * 64 + mi * 16 + lrow) * 32 + lgrp * 8);
#pragma unroll
    for (int ni = 0; ni < 4; ++ni)
      bfr[ni] = *reinterpret_cast<const bf16x8*>(Bs + (size_t)(wn * 64 + ni * 16 + lrow) * 32 + lgrp * 8);
#pragma unroll
    for (int mi = 0; mi < 4; ++mi)
#pragma unroll
      for (int ni = 0; ni < 4; ++ni)
        acc[mi][ni] = mfma16(af[mi], bfr[ni], acc[mi][ni]);
  }

  int r0 = bm + wm * 64, c0 = bn + wn * 64;
#pragma unroll
  for (int ni = 0; ni < 4; ++ni) {
    int col = c0 + ni * 16 + lrow;
    float bv = bias[col];
#pragma unroll
    for (int mi = 0; mi < 4; ++mi) {
      int rowb = r0 + mi * 16 + lgrp * 4;
      if (EPI == 2) {
        float* op = (float*)outp;
#pragma unroll
        for (int r = 0; r < 4; ++r)
          op[(size_t)(rowb + r) * Ndim + col] = acc[mi][ni][r] + bv;
      } else {
        int b = rowb >> 11, t = rowb & 2047;
        int which = col >> 10, cc = col & 1023;
        int h = cc >> 6, d = cc & 63;
        if (which == 2) {
          ushort4 pk;
          pk.x = f2bf(acc[mi][ni][0] + bv);
          pk.y = f2bf(acc[mi][ni][1] + bv);
          pk.z = f2bf(acc[mi][ni][2] + bv);
          pk.w = f2bf(acc[mi][ni][3] + bv);
          *reinterpret_cast<ushort4*>(vtbuf + ((size_t)((b * 16 + h) * 64 + d)) * T_ + t) = pk;
        } else {
          unsigned short* dst = (which == 0) ? qbuf : kbuf;
          size_t base = ((size_t)(b * 16 + h) * T_ + t) * DH_ + d;
#pragma unroll
          for (int r = 0; r < 4; ++r)
            dst[base + (size_t)r * DH_] = f2bf(acc[mi][ni][r] + bv);
        }
      }
    }
  }
}

// ---- flash attention: swapped QK^T, in-register softmax (T12) ----
// One 64-row q-tile per block, 4 waves x 16 rows; K LDS rows bit-permuted so
// cvt_pk + permlane32_swap produces the PV A-operand without any LDS round-trip.
__global__ __launch_bounds__(256, 4) void attn_kernel(
    const unsigned short* __restrict__ qbuf,
    const unsigned short* __restrict__ kbuf,
    const unsigned short* __restrict__ vtbuf,
    unsigned short* __restrict__ attno) {
  __shared__ __attribute__((aligned(16))) unsigned short Ks[64 * 64];
  __shared__ __attribute__((aligned(16))) unsigned short Vts[64 * 64];

  int tid = threadIdx.x;
  int lane = tid & 63, w = tid >> 6;
  int lrow = lane & 15, lgrp = lane >> 4;

  int g = blockIdx.x;
  int s = g >> 8;                                 // CU-mate slot
  int p = (g >> 3) & 7;
  int bh = (g & 7) | (((g >> 6) & 3) << 3);       // head: low bits -> XCD locality
  int qb = (s == 0) ? p : (s == 1) ? (31 - p) : (s == 2) ? (8 + p) : (23 - p);
  int wq0 = qb * 64 + w * 16;
  int nkb = qb + 1;

  const unsigned short* Qb = qbuf + (size_t)bh * T_ * DH_;
  const unsigned short* Kb = kbuf + (size_t)bh * T_ * DH_;
  const unsigned short* Vb = vtbuf + (size_t)bh * DH_ * T_;

  // staging geometry: K rows permuted (kperm), V rows natural
  int srow0 = tid >> 3, scol = tid & 7;
  int srow1 = srow0 + 32;
  int pk0 = kperm(srow0), pk1 = kperm(srow1);
  int soffK0 = pk0 * 128 + ((scol * 16) ^ ((pk0 & 7) << 4));
  int soffK1 = pk1 * 128 + ((scol * 16) ^ ((pk1 & 7) << 4));
  int soffV0 = srow0 * 128 + ((scol * 16) ^ ((srow0 & 7) << 4));
  int soffV1 = srow1 * 128 + ((scol * 16) ^ ((srow1 & 7) << 4));

  const float SC = 0.125f * 1.44269504f;  // scale * log2(e)
  // this lane's S^T register kv-base: chunks {kvbase+0..7, kvbase+16..23}
  int kvbase = ((lgrp & 1) << 3) | ((lgrp >> 1) << 5);
  const int koff[4] = {0, 4, 16, 20};     // kv offset of sreg[ni]

  bf16x8 qf[2];
#pragma unroll
  for (int ks = 0; ks < 2; ++ks)
    qf[ks] = *reinterpret_cast<const bf16x8*>(
        Qb + (size_t)(wq0 + lrow) * DH_ + ks * 32 + lgrp * 8);

  f32x4 o[4] = {};
  float m_run = -1e30f, l_run = 0.f;

  bf16x8 sk0, sk1, sv0, sv1;
  auto stage_load = [&](int kb) {
    sk0 = *reinterpret_cast<const bf16x8*>(Kb + (size_t)(kb * 64 + srow0) * DH_ + scol * 8);
    sk1 = *reinterpret_cast<const bf16x8*>(Kb + (size_t)(kb * 64 + srow1) * DH_ + scol * 8);
    sv0 = *reinterpret_cast<const bf16x8*>(Vb + (size_t)srow0 * T_ + kb * 64 + scol * 8);
    sv1 = *reinterpret_cast<const bf16x8*>(Vb + (size_t)srow1 * T_ + kb * 64 + scol * 8);
  };
  auto stage_write = [&]() {
    *reinterpret_cast<bf16x8*>((char*)Ks + soffK0) = sk0;
    *reinterpret_cast<bf16x8*>((char*)Ks + soffK1) = sk1;
    *reinterpret_cast<bf16x8*>((char*)Vts + soffV0) = sv0;
    *reinterpret_cast<bf16x8*>((char*)Vts + soffV1) = sv1;
  };

  stage_load(0);
#pragma unroll 1
  for (int kb = 0; kb < nkb; ++kb) {
    if (kb > 0) __syncthreads();   // prev iter's LDS reads done
    stage_write();
    __syncthreads();               // staged K/V visible
    if (kb + 1 < nkb) stage_load(kb + 1);

    // S^T = K @ Q^T : lane owns q-row (lane&15), kv per (ni,r) = kvbase+koff[ni]+r
    f32x4 sreg[4] = {};
#pragma unroll
    for (int ks = 0; ks < 2; ++ks) {
      bf16x8 kf[4];
#pragma unroll
      for (int ni = 0; ni < 4; ++ni) {
        int kr = ni * 16 + lrow;
        int off = kr * 128 + (((ks * 32 + lgrp * 8) * 2) ^ ((kr & 7) << 4));
        kf[ni] = *reinterpret_cast<const bf16x8*>((const char*)Ks + off);
      }
#pragma unroll
      for (int ni = 0; ni < 4; ++ni)
        sreg[ni] = mfma16(kf[ni], qf[ks], sreg[ni]);
    }

    if (kb == qb) {  // causal mask on the diagonal tile (raw-score domain)
      int q = wq0 + lrow;
#pragma unroll
      for (int ni = 0; ni < 4; ++ni) {
        int kvb = kb * 64 + kvbase + koff[ni];
#pragma unroll
        for (int r = 0; r < 4; ++r)
          if (kvb + r > q) sreg[ni][r] = -1e30f;
      }
    }

    // row max: in-lane vector tree + 2 cross-group shfls
    f32x4 tm = vmax4(vmax4(sreg[0], sreg[1]), vmax4(sreg[2], sreg[3]));
    float pm = fmaxf(fmaxf(tm[0], tm[1]), fmaxf(tm[2], tm[3]));
    pm = fmaxf(pm, __shfl_xor(pm, 16));
    pm = fmaxf(pm, __shfl_xor(pm, 32));
    float mnew = fmaxf(m_run, pm);
    float alpha = __builtin_amdgcn_exp2f((m_run - mnew) * SC);
    m_run = mnew;
    float msc = mnew * SC;

    f32x4 e[4];
#pragma unroll
    for (int ni = 0; ni < 4; ++ni)
#pragma unroll
      for (int r = 0; r < 4; ++r)
        e[ni][r] = __builtin_amdgcn_exp2f(sreg[ni][r] * SC - msc);

    f32x4 ts = e[0] + e[1] + e[2] + e[3];
    float rs = (ts[0] + ts[1]) + (ts[2] + ts[3]);
    rs += __shfl_xor(rs, 16);
    rs += __shfl_xor(rs, 32);
    l_run = l_run * alpha + rs;

    // P -> PV A-operand: 8 cvt_pk + 4 permlane32_swap (no LDS)
    unsigned int Aw[4], Bw[4];
    Aw[0] = cvtpk_bf16(e[0][0], e[0][1]); Aw[1] = cvtpk_bf16(e[0][2], e[0][3]);
    Aw[2] = cvtpk_bf16(e[1][0], e[1][1]); Aw[3] = cvtpk_bf16(e[1][2], e[1][3]);
    Bw[0] = cvtpk_bf16(e[2][0], e[2][1]); Bw[1] = cvtpk_bf16(e[2][2], e[2][3]);
    Bw[2] = cvtpk_bf16(e[3][0], e[3][1]); Bw[3] = cvtpk_bf16(e[3][2], e[3][3]);
    u32x4 p0v, p1v;
#pragma unroll
    for (int ww = 0; ww < 4; ++ww) {
      auto sw = __builtin_amdgcn_permlane32_swap(Aw[ww], Bw[ww], false, false);
      p0v[ww] = sw[0];
      p1v[ww] = sw[1];
    }
    bf16x8 pa[2];
    pa[0] = __builtin_bit_cast(bf16x8, p0v);
    pa[1] = __builtin_bit_cast(bf16x8, p1v);

    // broadcast alpha to output-row layout and rescale O
    float av[4];
#pragma unroll
    for (int r = 0; r < 4; ++r) av[r] = __shfl(alpha, lgrp * 4 + r);
#pragma unroll
    for (int di = 0; di < 4; ++di)
#pragma unroll
      for (int r = 0; r < 4; ++r)
        o[di][r] *= av[r];

    // PV: O += P @ V
#pragma unroll
    for (int ks = 0; ks < 2; ++ks) {
      bf16x8 vf[4];
#pragma unroll
      for (int di = 0; di < 4; ++di) {
        int vr = di * 16 + lrow;
        int off = vr * 128 + (((ks * 32 + lgrp * 8) * 2) ^ ((vr & 7) << 4));
        vf[di] = *reinterpret_cast<const bf16x8*>((const char*)Vts + off);
      }
#pragma unroll
      for (int di = 0; di < 4; ++di)
        o[di] = mfma16(pa[ks], vf[di], o[di]);
    }
  }

  int b = bh >> 4, h = bh & 15;
  float linv = 1.0f / l_run;
  float lr[4];
#pragma unroll
  for (int r = 0; r < 4; ++r) lr[r] = __shfl(linv, lgrp * 4 + r);
#pragma unroll
  for (int r = 0; r < 4; ++r) {
    int q = wq0 + lgrp * 4 + r;
    size_t base = ((size_t)(b * T_ + q)) * C_ + h * 64 + lrow;
#pragma unroll
    for (int di = 0; di < 4; ++di)
      attno[base + (size_t)di * 16] = f2bf(o[di][r] * lr[r]);
  }
}

extern "C" void kernel_launch(void* const* d_in, const int* in_sizes, int n_in,
                              void* d_out, int out_size, void* d_ws, size_t ws_size,
                              hipStream_t stream) {
  const float* x      = (const float*)d_in[0];
  const float* w_qkv  = (const float*)d_in[1];
  const float* b_qkv  = (const float*)d_in[2];
  const float* w_proj = (const float*)d_in[3];
  const float* b_proj = (const float*)d_in[4];

  char* ws = (char*)d_ws;
  unsigned short* xb     = (unsigned short*)(ws + 0);
  unsigned short* wqkvT  = (unsigned short*)(ws + 8388608);
  unsigned short* wprojT = (unsigned short*)(ws + 14680064);
  unsigned short* qbuf   = (unsigned short*)(ws + 16777216);
  unsigned short* kbuf   = (unsigned short*)(ws + 25165824);
  unsigned short* vtbuf  = (unsigned short*)(ws + 33554432);
  unsigned short* attno  = (unsigned short*)(ws + 41943040);

  cast_kernel<<<4096, 256, 0, stream>>>(x, xb, 1048576);
  transpose_cast_kernel<<<dim3(96, 32), dim3(32, 8), 0, stream>>>(w_qkv, wqkvT, 1024, 3072);
  transpose_cast_kernel<<<dim3(32, 32), dim3(32, 8), 0, stream>>>(w_proj, wprojT, 1024, 1024);
  gemm_bt<1><<<dim3(24, 32), 256, 0, stream>>>(xb, wqkvT, b_qkv, nullptr,
                                               4096, 3072, 1024, qbuf, kbuf, vtbuf);
  attn_kernel<<<dim3(1024), 256, 0, stream>>>(qbuf, kbuf, vtbuf, attno);
  gemm_bt<2><<<dim3(8, 32), 256, 0, stream>>>(attno, wprojT, b_proj, d_out,
                                              4096, 1024, 1024, nullptr, nullptr, nullptr);
}

// Round 5
// 116.612 us; speedup vs baseline: 1.6771x; 1.0056x over previous
//
#include <hip/hip_runtime.h>
#include <hip/hip_bf16.h>

#define B_ 2
#define T_ 2048
#define C_ 1024
#define H_ 16
#define DH_ 64

typedef __attribute__((ext_vector_type(8))) short bf16x8;
typedef __attribute__((ext_vector_type(4))) float f32x4;
typedef __attribute__((ext_vector_type(4))) unsigned int u32x4;

#define DEVI static __device__ __forceinline__

DEVI unsigned short f2bf(float f) {
  unsigned int u = __float_as_uint(f);
  u = (u + 0x7fffu + ((u >> 16) & 1u)) >> 16;
  return (unsigned short)u;
}

DEVI f32x4 mfma16(bf16x8 a, bf16x8 b, f32x4 c) {
  return __builtin_amdgcn_mfma_f32_16x16x32_bf16(a, b, c, 0, 0, 0);
}

DEVI void gload_lds16(const unsigned short* g, unsigned short* l) {
  __builtin_amdgcn_global_load_lds(
      (const __attribute__((address_space(1))) unsigned int*)g,
      (__attribute__((address_space(3))) unsigned int*)l, 16, 0, 0);
}

DEVI unsigned int cvtpk_bf16(float lo, float hi) {
  unsigned int r;
  asm("v_cvt_pk_bf16_f32 %0, %1, %2" : "=v"(r) : "v"(lo), "v"(hi));
  return r;
}

DEVI f32x4 vmax4(f32x4 a, f32x4 b) {
  f32x4 r;
  r[0] = fmaxf(a[0], b[0]); r[1] = fmaxf(a[1], b[1]);
  r[2] = fmaxf(a[2], b[2]); r[3] = fmaxf(a[3], b[3]);
  return r;
}

// K-row permutation for attn (see R3)
DEVI int kperm(int kv) {
  return (kv & 3) | (((kv >> 3) & 1) << 2) | (((kv >> 5) & 1) << 3) |
         (((kv >> 2) & 1) << 4) | (((kv >> 4) & 1) << 5);
}

// ---- fp32 -> bf16 cast ----
__global__ void cast_kernel(const float* __restrict__ in,
                            unsigned short* __restrict__ out, int n4) {
  int i = blockIdx.x * blockDim.x + threadIdx.x;
  if (i >= n4) return;
  float4 v = reinterpret_cast<const float4*>(in)[i];
  ushort4 o;
  o.x = f2bf(v.x); o.y = f2bf(v.y); o.z = f2bf(v.z); o.w = f2bf(v.w);
  reinterpret_cast<ushort4*>(out)[i] = o;
}

// ---- transpose + cast: in[R][C] fp32 -> out[C][R] bf16 ----
__global__ void transpose_cast_kernel(const float* __restrict__ in,
                                      unsigned short* __restrict__ out,
                                      int R, int C) {
  __shared__ float tile[32][33];
  int c0 = blockIdx.x * 32, r0 = blockIdx.y * 32;
  int tx = threadIdx.x, ty = threadIdx.y;
#pragma unroll
  for (int j = 0; j < 32; j += 8)
    tile[ty + j][tx] = in[(size_t)(r0 + ty + j) * C + c0 + tx];
  __syncthreads();
#pragma unroll
  for (int j = 0; j < 32; j += 8)
    out[(size_t)(c0 + ty + j) * R + r0 + tx] = f2bf(tile[tx][ty + j]);
}

// ---- GEMM C[M,N] = A[M,K] @ Bt[N,K]^T + bias ----
// Ring-4 LDS, 2-tiles-ahead prefetch, counted vmcnt (no drain), row-pair
// XOR swizzle (conflict-free ds_read_b128), setprio around MFMA cluster.
// LDS layout: rows packed 2/128B line; element (row,kc8) at byte
//   (row>>1)*128 + ((((row&1)<<6)|(kc8/8)<<4) ^ (((row>>1)&7)<<4))
// Staged via pre-swizzled GLOBAL source, linear gload_lds dest (rule #21).
template <int EPI>
__global__ __launch_bounds__(256, 2) void gemm_bt(
    const unsigned short* __restrict__ A, const unsigned short* __restrict__ Bt,
    const float* __restrict__ bias, void* __restrict__ outp,
    int Mdim, int Ndim, int Kdim,
    unsigned short* __restrict__ qbuf, unsigned short* __restrict__ kbuf,
    unsigned short* __restrict__ vtbuf) {
  __shared__ __attribute__((aligned(16))) unsigned short As[4][128 * 32];
  __shared__ __attribute__((aligned(16))) unsigned short Bs[4][128 * 32];
  int tid = threadIdx.x;
  int lane = tid & 63, w = tid >> 6;
  int wm = w >> 1, wn = w & 1;
  int lrow = lane & 15, lgrp = lane >> 4;
  int bm = blockIdx.y * 128, bn = blockIdx.x * 128;
  const unsigned short* Ab = A + (size_t)bm * Kdim;
  const unsigned short* Bb = Bt + (size_t)bn * Kdim;

  // staging: chunk p -> (row, kc) via swizzle-inverse
  int srow[2], skc[2], sdst[2];
#pragma unroll
  for (int it = 0; it < 2; ++it) {
    int p = tid + it * 256;
    int rp = p >> 3;
    int win = ((p & 7) << 4) ^ ((rp & 7) << 4);
    srow[it] = (rp << 1) + (win >> 6);
    skc[it] = (win & 63) >> 1;
    sdst[it] = p * 8;
  }

  // frag-read byte offsets
  int aoff[4], boff[4];
#pragma unroll
  for (int i = 0; i < 4; ++i) {
    int ra = wm * 64 + i * 16 + lrow;
    aoff[i] = (ra >> 1) * 128 + (((((ra & 1) << 6) | (lgrp << 4))) ^ (((ra >> 1) & 7) << 4));
    int rb = wn * 64 + i * 16 + lrow;
    boff[i] = (rb >> 1) * 128 + (((((rb & 1) << 6) | (lgrp << 4))) ^ (((rb >> 1) & 7) << 4));
  }

  f32x4 acc[4][4] = {};
  int nk = Kdim >> 5;

  auto stage = [&](int kt) {
    int slot = kt & 3, k0 = kt << 5;
#pragma unroll
    for (int it = 0; it < 2; ++it) {
      gload_lds16(Ab + (size_t)srow[it] * Kdim + k0 + skc[it], As[slot] + sdst[it]);
      gload_lds16(Bb + (size_t)srow[it] * Kdim + k0 + skc[it], Bs[slot] + sdst[it]);
    }
  };

  stage(0);
  stage(1);
#pragma unroll 1
  for (int t = 0; t < nk; ++t) {
    if (t + 2 < nk) {
      stage(t + 2);
      asm volatile("s_waitcnt vmcnt(8)" ::: "memory");   // tile t landed; t+1,t+2 fly
    } else if (t + 1 < nk) {
      asm volatile("s_waitcnt vmcnt(4)" ::: "memory");   // tile t landed; t+1 flies
    } else {
      asm volatile("s_waitcnt vmcnt(0)" ::: "memory");
    }
    __builtin_amdgcn_s_barrier();
    const char* Asl = (const char*)As[t & 3];
    const char* Bsl = (const char*)Bs[t & 3];
    bf16x8 af[4], bfr[4];
#pragma unroll
    for (int mi = 0; mi < 4; ++mi)
      af[mi] = *reinterpret_cast<const bf16x8*>(Asl + aoff[mi]);
#pragma unroll
    for (int ni = 0; ni < 4; ++ni)
      bfr[ni] = *reinterpret_cast<const bf16x8*>(Bsl + boff[ni]);
    __builtin_amdgcn_s_setprio(1);
#pragma unroll
    for (int mi = 0; mi < 4; ++mi)
#pragma unroll
      for (int ni = 0; ni < 4; ++ni)
        acc[mi][ni] = mfma16(af[mi], bfr[ni], acc[mi][ni]);
    __builtin_amdgcn_s_setprio(0);
  }

  int r0 = bm + wm * 64, c0 = bn + wn * 64;
#pragma unroll
  for (int ni = 0; ni < 4; ++ni) {
    int col = c0 + ni * 16 + lrow;
    float bv = bias[col];
#pragma unroll
    for (int mi = 0; mi < 4; ++mi) {
      int rowb = r0 + mi * 16 + lgrp * 4;
      if (EPI == 2) {
        float* op = (float*)outp;
#pragma unroll
        for (int r = 0; r < 4; ++r)
          op[(size_t)(rowb + r) * Ndim + col] = acc[mi][ni][r] + bv;
      } else {
        int b = rowb >> 11, t = rowb & 2047;
        int which = col >> 10, cc = col & 1023;
        int h = cc >> 6, d = cc & 63;
        if (which == 2) {
          ushort4 pk;
          pk.x = f2bf(acc[mi][ni][0] + bv);
          pk.y = f2bf(acc[mi][ni][1] + bv);
          pk.z = f2bf(acc[mi][ni][2] + bv);
          pk.w = f2bf(acc[mi][ni][3] + bv);
          *reinterpret_cast<ushort4*>(vtbuf + ((size_t)((b * 16 + h) * 64 + d)) * T_ + t) = pk;
        } else {
          unsigned short* dst = (which == 0) ? qbuf : kbuf;
          size_t base = ((size_t)(b * 16 + h) * T_ + t) * DH_ + d;
#pragma unroll
          for (int r = 0; r < 4; ++r)
            dst[base + (size_t)r * DH_] = f2bf(acc[mi][ni][r] + bv);
        }
      }
    }
  }
}

// ---- flash attention: swapped QK^T, in-register softmax (T12) ----
__global__ __launch_bounds__(256, 4) void attn_kernel(
    const unsigned short* __restrict__ qbuf,
    const unsigned short* __restrict__ kbuf,
    const unsigned short* __restrict__ vtbuf,
    unsigned short* __restrict__ attno) {
  __shared__ __attribute__((aligned(16))) unsigned short Ks[64 * 64];
  __shared__ __attribute__((aligned(16))) unsigned short Vts[64 * 64];

  int tid = threadIdx.x;
  int lane = tid & 63, w = tid >> 6;
  int lrow = lane & 15, lgrp = lane >> 4;

  int g = blockIdx.x;
  int s = g >> 8;                                 // CU-mate slot
  int p = (g >> 3) & 7;
  int bh = (g & 7) | (((g >> 6) & 3) << 3);       // head: low bits -> XCD locality
  int qb = (s == 0) ? p : (s == 1) ? (31 - p) : (s == 2) ? (8 + p) : (23 - p);
  int wq0 = qb * 64 + w * 16;
  int nkb = qb + 1;

  const unsigned short* Qb = qbuf + (size_t)bh * T_ * DH_;
  const unsigned short* Kb = kbuf + (size_t)bh * T_ * DH_;
  const unsigned short* Vb = vtbuf + (size_t)bh * DH_ * T_;

  int srow0 = tid >> 3, scol = tid & 7;
  int srow1 = srow0 + 32;
  int pk0 = kperm(srow0), pk1 = kperm(srow1);
  int soffK0 = pk0 * 128 + ((scol * 16) ^ ((pk0 & 7) << 4));
  int soffK1 = pk1 * 128 + ((scol * 16) ^ ((pk1 & 7) << 4));
  int soffV0 = srow0 * 128 + ((scol * 16) ^ ((srow0 & 7) << 4));
  int soffV1 = srow1 * 128 + ((scol * 16) ^ ((srow1 & 7) << 4));

  const float SC = 0.125f * 1.44269504f;
  int kvbase = ((lgrp & 1) << 3) | ((lgrp >> 1) << 5);
  const int koff[4] = {0, 4, 16, 20};

  bf16x8 qf[2];
#pragma unroll
  for (int ks = 0; ks < 2; ++ks)
    qf[ks] = *reinterpret_cast<const bf16x8*>(
        Qb + (size_t)(wq0 + lrow) * DH_ + ks * 32 + lgrp * 8);

  f32x4 o[4] = {};
  float m_run = -1e30f, l_run = 0.f;

  bf16x8 sk0, sk1, sv0, sv1;
  auto stage_load = [&](int kb) {
    sk0 = *reinterpret_cast<const bf16x8*>(Kb + (size_t)(kb * 64 + srow0) * DH_ + scol * 8);
    sk1 = *reinterpret_cast<const bf16x8*>(Kb + (size_t)(kb * 64 + srow1) * DH_ + scol * 8);
    sv0 = *reinterpret_cast<const bf16x8*>(Vb + (size_t)srow0 * T_ + kb * 64 + scol * 8);
    sv1 = *reinterpret_cast<const bf16x8*>(Vb + (size_t)srow1 * T_ + kb * 64 + scol * 8);
  };
  auto stage_write = [&]() {
    *reinterpret_cast<bf16x8*>((char*)Ks + soffK0) = sk0;
    *reinterpret_cast<bf16x8*>((char*)Ks + soffK1) = sk1;
    *reinterpret_cast<bf16x8*>((char*)Vts + soffV0) = sv0;
    *reinterpret_cast<bf16x8*>((char*)Vts + soffV1) = sv1;
  };

  stage_load(0);
#pragma unroll 1
  for (int kb = 0; kb < nkb; ++kb) {
    if (kb > 0) __syncthreads();
    stage_write();
    __syncthreads();
    if (kb + 1 < nkb) stage_load(kb + 1);

    f32x4 sreg[4] = {};
#pragma unroll
    for (int ks = 0; ks < 2; ++ks) {
      bf16x8 kf[4];
#pragma unroll
      for (int ni = 0; ni < 4; ++ni) {
        int kr = ni * 16 + lrow;
        int off = kr * 128 + (((ks * 32 + lgrp * 8) * 2) ^ ((kr & 7) << 4));
        kf[ni] = *reinterpret_cast<const bf16x8*>((const char*)Ks + off);
      }
#pragma unroll
      for (int ni = 0; ni < 4; ++ni)
        sreg[ni] = mfma16(kf[ni], qf[ks], sreg[ni]);
    }

    if (kb == qb) {
      int q = wq0 + lrow;
#pragma unroll
      for (int ni = 0; ni < 4; ++ni) {
        int kvb = kb * 64 + kvbase + koff[ni];
#pragma unroll
        for (int r = 0; r < 4; ++r)
          if (kvb + r > q) sreg[ni][r] = -1e30f;
      }
    }

    f32x4 tm = vmax4(vmax4(sreg[0], sreg[1]), vmax4(sreg[2], sreg[3]));
    float pm = fmaxf(fmaxf(tm[0], tm[1]), fmaxf(tm[2], tm[3]));
    pm = fmaxf(pm, __shfl_xor(pm, 16));
    pm = fmaxf(pm, __shfl_xor(pm, 32));
    float mnew = fmaxf(m_run, pm);
    float alpha = __builtin_amdgcn_exp2f((m_run - mnew) * SC);
    m_run = mnew;
    float msc = mnew * SC;

    f32x4 e[4];
#pragma unroll
    for (int ni = 0; ni < 4; ++ni)
#pragma unroll
      for (int r = 0; r < 4; ++r)
        e[ni][r] = __builtin_amdgcn_exp2f(sreg[ni][r] * SC - msc);

    f32x4 ts = e[0] + e[1] + e[2] + e[3];
    float rs = (ts[0] + ts[1]) + (ts[2] + ts[3]);
    rs += __shfl_xor(rs, 16);
    rs += __shfl_xor(rs, 32);
    l_run = l_run * alpha + rs;

    unsigned int Aw[4], Bw[4];
    Aw[0] = cvtpk_bf16(e[0][0], e[0][1]); Aw[1] = cvtpk_bf16(e[0][2], e[0][3]);
    Aw[2] = cvtpk_bf16(e[1][0], e[1][1]); Aw[3] = cvtpk_bf16(e[1][2], e[1][3]);
    Bw[0] = cvtpk_bf16(e[2][0], e[2][1]); Bw[1] = cvtpk_bf16(e[2][2], e[2][3]);
    Bw[2] = cvtpk_bf16(e[3][0], e[3][1]); Bw[3] = cvtpk_bf16(e[3][2], e[3][3]);
    u32x4 p0v, p1v;
#pragma unroll
    for (int ww = 0; ww < 4; ++ww) {
      auto sw = __builtin_amdgcn_permlane32_swap(Aw[ww], Bw[ww], false, false);
      p0v[ww] = sw[0];
      p1v[ww] = sw[1];
    }
    bf16x8 pa[2];
    pa[0] = __builtin_bit_cast(bf16x8, p0v);
    pa[1] = __builtin_bit_cast(bf16x8, p1v);

    float av[4];
#pragma unroll
    for (int r = 0; r < 4; ++r) av[r] = __shfl(alpha, lgrp * 4 + r);
#pragma unroll
    for (int di = 0; di < 4; ++di)
#pragma unroll
      for (int r = 0; r < 4; ++r)
        o[di][r] *= av[r];

#pragma unroll
    for (int ks = 0; ks < 2; ++ks) {
      bf16x8 vf[4];
#pragma unroll
      for (int di = 0; di < 4; ++di) {
        int vr = di * 16 + lrow;
        int off = vr * 128 + (((ks * 32 + lgrp * 8) * 2) ^ ((vr & 7) << 4));
        vf[di] = *reinterpret_cast<const bf16x8*>((const char*)Vts + off);
      }
#pragma unroll
      for (int di = 0; di < 4; ++di)
        o[di] = mfma16(pa[ks], vf[di], o[di]);
    }
  }

  int b = bh >> 4, h = bh & 15;
  float linv = 1.0f / l_run;
  float lr[4];
#pragma unroll
  for (int r = 0; r < 4; ++r) lr[r] = __shfl(linv, lgrp * 4 + r);
#pragma unroll
  for (int r = 0; r < 4; ++r) {
    int q = wq0 + lgrp * 4 + r;
    size_t base = ((size_t)(b * T_ + q)) * C_ + h * 64 + lrow;
#pragma unroll
    for (int di = 0; di < 4; ++di)
      attno[base + (size_t)di * 16] = f2bf(o[di][r] * lr[r]);
  }
}

extern "C" void kernel_launch(void* const* d_in, const int* in_sizes, int n_in,
                              void* d_out, int out_size, void* d_ws, size_t ws_size,
                              hipStream_t stream) {
  const float* x      = (const float*)d_in[0];
  const float* w_qkv  = (const float*)d_in[1];
  const float* b_qkv  = (const float*)d_in[2];
  const float* w_proj = (const float*)d_in[3];
  const float* b_proj = (const float*)d_in[4];

  char* ws = (char*)d_ws;
  unsigned short* xb     = (unsigned short*)(ws + 0);
  unsigned short* wqkvT  = (unsigned short*)(ws + 8388608);
  unsigned short* wprojT = (unsigned short*)(ws + 14680064);
  unsigned short* qbuf   = (unsigned short*)(ws + 16777216);
  unsigned short* kbuf   = (unsigned short*)(ws + 25165824);
  unsigned short* vtbuf  = (unsigned short*)(ws + 33554432);
  unsigned short* attno  = (unsigned short*)(ws + 41943040);

  cast_kernel<<<4096, 256, 0, stream>>>(x, xb, 1048576);
  transpose_cast_kernel<<<dim3(96, 32), dim3(32, 8), 0, stream>>>(w_qkv, wqkvT, 1024, 3072);
  transpose_cast_kernel<<<dim3(32, 32), dim3(32, 8), 0, stream>>>(w_proj, wprojT, 1024, 1024);
  gemm_bt<1><<<dim3(24, 32), 256, 0, stream>>>(xb, wqkvT, b_qkv, nullptr,
                                               4096, 3072, 1024, qbuf, kbuf, vtbuf);
  attn_kernel<<<dim3(1024), 256, 0, stream>>>(qbuf, kbuf, vtbuf, attno);
  gemm_bt<2><<<dim3(8, 32), 256, 0, stream>>>(attno, wprojT, b_proj, d_out,
                                              4096, 1024, 1024, nullptr, nullptr, nullptr);
}